// Round 12
// baseline (361.894 us; speedup 1.0000x reference)
//
#include <hip/hip_runtime.h>
#include <hip/hip_bf16.h>
#include <math.h>

// Problem constants
#define CB 8        // batch
#define CN 2048     // seq len
#define CD 768      // dim
#define CDQKV 2304  // 3*dim
#define NG 49       // groups
#define SLD 2112    // padded K-row stride for P|a*gw concat (2048 + 64)

typedef unsigned short ushort_t;
typedef __attribute__((ext_vector_type(8))) short bf16x8;
typedef __attribute__((ext_vector_type(4))) float f32x4;

__device__ __forceinline__ float bf2f(ushort_t u) {
    unsigned int x = ((unsigned int)u) << 16;
    return __builtin_bit_cast(float, x);
}
__device__ __forceinline__ ushort_t f2bf(float f) {
    unsigned int u = __builtin_bit_cast(unsigned int, f);
    u += 0x7fff + ((u >> 16) & 1);   // RNE
    return (ushort_t)(u >> 16);
}
__device__ __forceinline__ ushort_t f2h(float f) {
    _Float16 h = (_Float16)f;
    return __builtin_bit_cast(ushort_t, h);
}
__device__ __forceinline__ float h2f(ushort_t u) {
    return (float)__builtin_bit_cast(_Float16, u);
}
__device__ __forceinline__ float sigmoidf_(float x) { return 1.f / (1.f + __expf(-x)); }

__device__ __forceinline__ void gload_lds16(const ushort_t* g, ushort_t* l) {
    __builtin_amdgcn_global_load_lds((const __attribute__((address_space(1))) void*)g,
                                     (__attribute__((address_space(3))) void*)l, 16, 0, 0);
}

// -------------------------------------------------------------------------
__global__ void ws_fail_marker(float* out) {
    if (threadIdx.x == 0 && blockIdx.x == 0) out[0] = 31337.0f;
}

// -------------------------------------------------------------------------
__global__ __launch_bounds__(256) void cast_bf16(const float* __restrict__ X,
                                                 ushort_t* __restrict__ XB, int n)
{
    int i = (blockIdx.x * 256 + threadIdx.x) * 8;
    if (i >= n) return;
    float4 a = *(const float4*)(X + i);
    float4 b = *(const float4*)(X + i + 4);
    ushort_t t[8];
    t[0] = f2bf(a.x); t[1] = f2bf(a.y); t[2] = f2bf(a.z); t[3] = f2bf(a.w);
    t[4] = f2bf(b.x); t[5] = f2bf(b.y); t[6] = f2bf(b.z); t[7] = f2bf(b.w);
    *(uint4*)(XB + i) = *(uint4*)t;
}

// -------------------------------------------------------------------------
__global__ __launch_bounds__(256) void wt_kernel(const float* __restrict__ W,
                                                 ushort_t* __restrict__ WT,
                                                 int rows, int cols)
{
    __shared__ ushort_t tile[64][72];
    const int bx = blockIdx.x, by = blockIdx.y;
    const int t = threadIdx.x;
    const int r = t >> 2, cp = (t & 3) * 16;
    const float* src = W + (size_t)(by * 64 + r) * cols + bx * 64 + cp;
    ushort_t tmp[16];
#pragma unroll
    for (int i = 0; i < 16; i += 4) {
        float4 v = *(const float4*)(src + i);
        tmp[i + 0] = f2bf(v.x); tmp[i + 1] = f2bf(v.y);
        tmp[i + 2] = f2bf(v.z); tmp[i + 3] = f2bf(v.w);
    }
    *(uint4*)&tile[r][cp] = *(uint4*)tmp;
    *(uint4*)&tile[r][cp + 8] = *(uint4*)(tmp + 8);
    __syncthreads();
#pragma unroll
    for (int i = 0; i < 16; i++) tmp[i] = tile[cp + i][r];
    ushort_t* dst = WT + (size_t)(bx * 64 + r) * rows + by * 64 + cp;
    *(uint4*)dst = *(uint4*)tmp;
    *(uint4*)(dst + 8) = *(uint4*)(tmp + 8);
}

// -------------------------------------------------------------------------
__global__ __launch_bounds__(256) void wgpt_kernel(const float* __restrict__ Wg,
                                                   ushort_t* __restrict__ WGPT)
{
    int idx = blockIdx.x * 256 + threadIdx.x;   // 64*768 = 49152
    if (idx >= 64 * CD) return;
    int gg = idx / CD, k = idx % CD;
    WGPT[idx] = (gg < NG) ? f2bf(Wg[(size_t)k * NG + gg]) : (ushort_t)0;
}

// =========================================================================
// 128x128 2-phase machinery (proven best measured structure this session):
// BK=64, 256 thr = 4 waves (2x2 of 64x64), double-buffered LDS via
// global_load_lds w=16, source-preswizzled XOR (rule #21), 2-barrier loop.
// =========================================================================
#define GEN_STAGE(dstA_, dstB_, kt_, Abase_, Bbase_, lda_, ldb_) do {          \
    _Pragma("unroll")                                                          \
    for (int _p = 0; _p < 4; _p++) {                                           \
        int _idx = _p * 256 + tid;                                             \
        int _row = _idx >> 3;                                                  \
        int _lsl = (_idx & 7) ^ (_row & 7);                                    \
        gload_lds16((Abase_) + (size_t)_row * (lda_) + (size_t)(kt_) * 64 + _lsl * 8, \
                    (dstA_) + _idx * 8);                                       \
        gload_lds16((Bbase_) + (size_t)_row * (ldb_) + (size_t)(kt_) * 64 + _lsl * 8, \
                    (dstB_) + _idx * 8);                                       \
    } } while (0)

#define G_COMPUTE(srcA_, srcB_) do {                                           \
    _Pragma("unroll")                                                          \
    for (int _ks = 0; _ks < 2; _ks++) {                                        \
        bf16x8 _af[4], _bf[4];                                                 \
        _Pragma("unroll")                                                      \
        for (int _f = 0; _f < 4; _f++) {                                       \
            int _ra = wr * 64 + _f * 16 + c;                                   \
            int _pa = (_ks * 4 + g) ^ (_ra & 7);                               \
            _af[_f] = *(const bf16x8*)((srcA_) + _ra * 64 + _pa * 8);          \
            int _rb = wc * 64 + _f * 16 + c;                                   \
            int _pb = (_ks * 4 + g) ^ (_rb & 7);                               \
            _bf[_f] = *(const bf16x8*)((srcB_) + _rb * 64 + _pb * 8);          \
        }                                                                      \
        _Pragma("unroll")                                                      \
        for (int _mf = 0; _mf < 4; _mf++)                                      \
            _Pragma("unroll")                                                  \
            for (int _nf = 0; _nf < 4; _nf++)                                  \
                acc[_mf * 4 + _nf] = __builtin_amdgcn_mfma_f32_16x16x32_bf16(  \
                    _af[_mf], _bf[_nf], acc[_mf * 4 + _nf], 0, 0, 0);          \
    } } while (0)

#define STAGE_A128(dst_, base_, ld_, kt_) do {                                 \
    _Pragma("unroll")                                                          \
    for (int _p = 0; _p < 4; _p++) {                                           \
        int _idx = _p * 256 + tid;                                             \
        int _row = _idx >> 3;                                                  \
        int _lsl = (_idx & 7) ^ (_row & 7);                                    \
        gload_lds16((base_) + (size_t)_row * (ld_) + (size_t)(kt_) * 64 + _lsl * 8, \
                    (dst_) + _idx * 8);                                        \
    } } while (0)

#define STAGE_B64(dst_, base_, ld_, kt_) do {                                  \
    _Pragma("unroll")                                                          \
    for (int _p = 0; _p < 2; _p++) {                                           \
        int _idx = _p * 256 + tid;                                             \
        int _row = _idx >> 3;                                                  \
        int _lsl = (_idx & 7) ^ (_row & 7);                                    \
        gload_lds16((base_) + (size_t)_row * (ld_) + (size_t)(kt_) * 64 + _lsl * 8, \
                    (dst_) + _idx * 8);                                        \
    } } while (0)

#define N64_COMPUTE(srcA_, srcB_) do {                                         \
    _Pragma("unroll")                                                          \
    for (int _ks = 0; _ks < 2; _ks++) {                                        \
        bf16x8 _af[2], _bf[4];                                                 \
        _Pragma("unroll")                                                      \
        for (int _f = 0; _f < 2; _f++) {                                       \
            int _ra = w * 32 + _f * 16 + c;                                    \
            int _pa = (_ks * 4 + g) ^ (_ra & 7);                               \
            _af[_f] = *(const bf16x8*)((srcA_) + _ra * 64 + _pa * 8);          \
        }                                                                      \
        _Pragma("unroll")                                                      \
        for (int _f = 0; _f < 4; _f++) {                                       \
            int _rb = _f * 16 + c;                                             \
            int _pb = (_ks * 4 + g) ^ (_rb & 7);                               \
            _bf[_f] = *(const bf16x8*)((srcB_) + _rb * 64 + _pb * 8);          \
        }                                                                      \
        _Pragma("unroll")                                                      \
        for (int _mf = 0; _mf < 2; _mf++)                                      \
            _Pragma("unroll")                                                  \
            for (int _nf = 0; _nf < 4; _nf++)                                  \
                acc[_mf * 4 + _nf] = __builtin_amdgcn_mfma_f32_16x16x32_bf16(  \
                    _af[_mf], _bf[_nf], acc[_mf * 4 + _nf], 0, 0, 0);          \
    } } while (0)

// -------------------------------------------------------------------------
// mfma_gemm: 128x128 C = A @ B^T (+bias), 2-phase.
// OUTMODE 0: split bf16 q/k/v + bias; v-segment blocks ALSO write the
//            transposed tile into VTt (stride SLD) via LDS bounce —
//            replaces the standalone vt_transpose kernel.
//         1: fp32 out + bias        (grid (128,6,1)).
//         2: bf16 out, per-batch A/B panels, K=2112 pv; 1-D grid (768),
//            batch-chunked XCD swizzle, n-fastest order (A-panel L2-hot).
// -------------------------------------------------------------------------
template <int OUTMODE, int NK, int LDA, int LDB>
__global__ __launch_bounds__(256, 2) void mfma_gemm(
    const ushort_t* __restrict__ Ag, const ushort_t* __restrict__ Bg,
    const float* __restrict__ bias,
    ushort_t* __restrict__ Qd, ushort_t* __restrict__ Kd, ushort_t* __restrict__ Vd,
    ushort_t* __restrict__ VTt,
    ushort_t* __restrict__ OB, float* __restrict__ OF)
{
    __shared__ __align__(16) ushort_t As[2][128 * 64];
    __shared__ __align__(16) ushort_t Bs[2][128 * 64];
    const int tid = threadIdx.x;
    const int lane = tid & 63;
    const int w = tid >> 6;
    const int c = lane & 15, g = lane >> 4;
    const int wr = w >> 1, wc = w & 1;

    int m0, n0, b;
    const ushort_t* Ab;
    const ushort_t* Bb;
    if (OUTMODE == 2) {
        // T1 batch-chunk swizzle: flat grid 768 = 96/XCD; n fastest so
        // consecutive blocks share the A (P) panel in L2.
        const int flat = blockIdx.x;
        const int idx = (flat & 7) * 96 + (flat >> 3);
        b = idx / 96;
        const int rem = idx % 96;
        m0 = (rem / 6) * 128;
        n0 = (rem % 6) * 128;
        Ab = Ag + ((size_t)b * CN + m0) * LDA;     // P rows, stride SLD
        Bb = Bg + ((size_t)b * CD + n0) * LDB;     // V^T rows (d), stride SLD
    } else {
        m0 = blockIdx.x * 128;
        n0 = blockIdx.y * 128;
        b = 0;
        Ab = Ag + (size_t)m0 * LDA;
        Bb = Bg + (size_t)n0 * LDB;
    }

    f32x4 acc[16];
#pragma unroll
    for (int i = 0; i < 16; i++) acc[i] = (f32x4){0.f, 0.f, 0.f, 0.f};

    GEN_STAGE(As[0], Bs[0], 0, Ab, Bb, LDA, LDB);
    __syncthreads();
#pragma unroll 1
    for (int kt = 0; kt < NK; kt++) {
        const int cur = kt & 1;
        if (kt < NK - 1) GEN_STAGE(As[cur ^ 1], Bs[cur ^ 1], kt + 1, Ab, Bb, LDA, LDB);
        G_COMPUTE(As[cur], Bs[cur]);
        __syncthreads();
    }

    if (OUTMODE == 0) {
        const int seg = n0 / CD;
        const int nl0 = n0 % CD;
        ushort_t* dst = (seg == 0) ? Qd : (seg == 1) ? Kd : Vd;
        ushort_t* T = (ushort_t*)As;   // 32 KB scratch, free after main loop
#pragma unroll
        for (int nf = 0; nf < 4; nf++) {
            float bv = bias[n0 + wc * 64 + nf * 16 + c];
            int n = nl0 + wc * 64 + nf * 16 + c;
            int nl = wc * 64 + nf * 16 + c;
#pragma unroll
            for (int mf = 0; mf < 4; mf++) {
#pragma unroll
                for (int r = 0; r < 4; r++) {
                    int ml = wr * 64 + mf * 16 + g * 4 + r;
                    ushort_t val = f2bf(acc[mf * 4 + nf][r] + bv);
                    dst[(size_t)(m0 + ml) * CD + n] = val;
                    if (seg == 2)
                        T[nl * 128 + (ml ^ ((nl & 7) << 4))] = val;   // XOR swz
                }
            }
        }
        if (seg == 2) {
            __syncthreads();
            const int d0 = n0 - 2 * CD;
            const int bb = m0 >> 11;
            const int tok0 = m0 & 2047;
            const int row = tid >> 1, half = tid & 1;
            ushort_t* dst2 = VTt + ((size_t)bb * CD + d0 + row) * SLD + tok0;
#pragma unroll
            for (int i = 0; i < 8; i++) {
                int m_log = half * 64 + i * 8;
                int phys = m_log ^ ((row & 7) << 4);
                *(uint4*)(dst2 + m_log) = *(const uint4*)(T + row * 128 + phys);
            }
        }
    } else if (OUTMODE == 1) {
#pragma unroll
        for (int nf = 0; nf < 4; nf++) {
            int n = n0 + wc * 64 + nf * 16 + c;
            float bv = bias[n];
#pragma unroll
            for (int mf = 0; mf < 4; mf++) {
#pragma unroll
                for (int r = 0; r < 4; r++) {
                    int m = m0 + wr * 64 + mf * 16 + g * 4 + r;
                    OF[(size_t)m * CD + n] = acc[mf * 4 + nf][r] + bv;
                }
            }
        }
    } else {
        ushort_t* OPb = OB + ((size_t)b * CN + m0) * CD;
#pragma unroll
        for (int nf = 0; nf < 4; nf++) {
            int n = n0 + wc * 64 + nf * 16 + c;
#pragma unroll
            for (int mf = 0; mf < 4; mf++) {
#pragma unroll
                for (int r = 0; r < 4; r++) {
                    int m = wr * 64 + mf * 16 + g * 4 + r;
                    OPb[(size_t)m * CD + n] = f2bf(acc[mf * 4 + nf][r]);
                }
            }
        }
    }
}

// -------------------------------------------------------------------------
// s_gemm: S = (q.k)*scale*G, fp16 out at row-stride SLD. 128^2, 2-phase,
// G-affinity via 32 upfront MFMAs with frags straight from global (L2-hot).
// 1-D grid (2048) with batch-chunked XCD swizzle (T1).
// -------------------------------------------------------------------------
__global__ __launch_bounds__(256, 2) void s_gemm(
    const ushort_t* __restrict__ Qb, const ushort_t* __restrict__ Kb,
    const ushort_t* __restrict__ GWP, ushort_t* __restrict__ S)
{
    __shared__ __align__(16) ushort_t As[2][128 * 64];
    __shared__ __align__(16) ushort_t Bs[2][128 * 64];
    const int tid = threadIdx.x;
    const int lane = tid & 63;
    const int w = tid >> 6;
    const int c = lane & 15, g = lane >> 4;
    const int wr = w >> 1, wc = w & 1;

    // T1 batch-chunk swizzle: flat grid 2048 = 256/XCD; idx>>8 = batch.
    const int flat = blockIdx.x;
    const int idx = (flat & 7) * 256 + (flat >> 3);
    const int b = idx >> 8;
    const int m0 = ((idx >> 4) & 15) * 128;
    const int n0 = (idx & 15) * 128;

    const ushort_t* Ab = Qb + ((size_t)b * CN + m0) * CD;
    const ushort_t* Bb = Kb + ((size_t)b * CN + n0) * CD;

    f32x4 acc[16], gacc[16];
#pragma unroll
    for (int i = 0; i < 16; i++) {
        acc[i] = (f32x4){0.f, 0.f, 0.f, 0.f};
        gacc[i] = (f32x4){0.f, 0.f, 0.f, 0.f};
    }

    GEN_STAGE(As[0], Bs[0], 0, Ab, Bb, CD, CD);

    {
        const ushort_t* Gq = GWP + ((size_t)b * CN + m0) * 64;
        const ushort_t* Gk = GWP + ((size_t)b * CN + n0) * 64;
        bf16x8 gqf[2][4], gkf[2][4];
#pragma unroll
        for (int ks = 0; ks < 2; ks++)
#pragma unroll
            for (int f = 0; f < 4; f++) {
                gqf[ks][f] = *(const bf16x8*)(Gq + (size_t)(wr * 64 + f * 16 + c) * 64 + ks * 32 + g * 8);
                gkf[ks][f] = *(const bf16x8*)(Gk + (size_t)(wc * 64 + f * 16 + c) * 64 + ks * 32 + g * 8);
            }
#pragma unroll
        for (int ks = 0; ks < 2; ks++)
#pragma unroll
            for (int mf = 0; mf < 4; mf++)
#pragma unroll
                for (int nf = 0; nf < 4; nf++)
                    gacc[mf * 4 + nf] = __builtin_amdgcn_mfma_f32_16x16x32_bf16(
                        gqf[ks][mf], gkf[ks][nf], gacc[mf * 4 + nf], 0, 0, 0);
    }

    __syncthreads();
#pragma unroll 1
    for (int kt = 0; kt < 12; kt++) {
        const int cur = kt & 1;
        if (kt < 11) GEN_STAGE(As[cur ^ 1], Bs[cur ^ 1], kt + 1, Ab, Bb, CD, CD);
        G_COMPUTE(As[cur], Bs[cur]);
        __syncthreads();
    }

    ushort_t* Sb = S + ((size_t)b * CN + m0) * SLD + n0;
    const float scale = 0.03608439182435161f;  // 768^-0.5
#pragma unroll
    for (int nf = 0; nf < 4; nf++) {
        int n = wc * 64 + nf * 16 + c;
#pragma unroll
        for (int mf = 0; mf < 4; mf++) {
#pragma unroll
            for (int r = 0; r < 4; r++) {
                int m = wr * 64 + mf * 16 + g * 4 + r;
                float z = acc[mf * 4 + nf][r] * scale * gacc[mf * 4 + nf][r];
                Sb[(size_t)m * SLD + n] = f2h(z);
            }
        }
    }
}

// -------------------------------------------------------------------------
// gw_gemm: gw = softmax49(gelu_exact(v @ W_gp)) via MFMA, fused epilogue.
// -------------------------------------------------------------------------
__global__ __launch_bounds__(256, 2) void gw_gemm(
    const ushort_t* __restrict__ Vb, const ushort_t* __restrict__ WGPT,
    ushort_t* __restrict__ GWP, ushort_t* __restrict__ GWT)
{
    __shared__ __align__(16) ushort_t As[2][128 * 64];
    __shared__ __align__(16) ushort_t Bs[2][64 * 64];
    const int tid = threadIdx.x;
    const int lane = tid & 63;
    const int w = tid >> 6;
    const int c = lane & 15, g = lane >> 4;
    const int row0 = blockIdx.x * 128;
    const ushort_t* Ab = Vb + (size_t)row0 * CD;

    f32x4 acc[8];
#pragma unroll
    for (int i = 0; i < 8; i++) acc[i] = (f32x4){0.f, 0.f, 0.f, 0.f};

    STAGE_A128(As[0], Ab, CD, 0);
    STAGE_B64(Bs[0], WGPT, CD, 0);
    __syncthreads();
#pragma unroll 1
    for (int kt = 0; kt < 12; kt++) {
        const int cur = kt & 1;
        if (kt < 11) {
            STAGE_A128(As[cur ^ 1], Ab, CD, kt + 1);
            STAGE_B64(Bs[cur ^ 1], WGPT, CD, kt + 1);
        }
        N64_COMPUTE(As[cur], Bs[cur]);
        __syncthreads();
    }

    float gl[2][4][4];
#pragma unroll
    for (int mf = 0; mf < 2; mf++)
#pragma unroll
        for (int nf = 0; nf < 4; nf++) {
            int col = nf * 16 + c;
#pragma unroll
            for (int rr = 0; rr < 4; rr++) {
                float xx = acc[mf * 4 + nf][rr];
                float ge = 0.5f * xx * (1.f + erff(xx * 0.7071067811865475f));
                gl[mf][nf][rr] = (col < NG) ? ge : -1e30f;
            }
        }
#pragma unroll
    for (int mf = 0; mf < 2; mf++) {
#pragma unroll
        for (int rr = 0; rr < 4; rr++) {
            float m = fmaxf(fmaxf(gl[mf][0][rr], gl[mf][1][rr]),
                            fmaxf(gl[mf][2][rr], gl[mf][3][rr]));
#pragma unroll
            for (int s = 1; s < 16; s <<= 1) m = fmaxf(m, __shfl_xor(m, s, 64));
            float ssum = 0.f;
#pragma unroll
            for (int nf = 0; nf < 4; nf++) {
                int col = nf * 16 + c;
                float e = (col < NG) ? __expf(gl[mf][nf][rr] - m) : 0.f;
                gl[mf][nf][rr] = e;
                ssum += e;
            }
#pragma unroll
            for (int s = 1; s < 16; s <<= 1) ssum += __shfl_xor(ssum, s, 64);
            float inv = 1.f / ssum;
            int row = row0 + w * 32 + mf * 16 + g * 4 + rr;
            int bb = row >> 11, nn = row & 2047;
#pragma unroll
            for (int nf = 0; nf < 4; nf++) {
                int col = nf * 16 + c;
                ushort_t wv = f2bf(gl[mf][nf][rr] * inv);
                GWP[(size_t)row * 64 + col] = wv;
                GWT[((size_t)bb * 64 + col) * CN + nn] = wv;
            }
        }
    }
}

// -------------------------------------------------------------------------
// z_gemm: Z^T[b][d][g] = sum_n vt[b][d][n]*gwt[b][g][n]; writes the TAIL
// columns (2048..2111) of the stride-2112 vt buffer.
// -------------------------------------------------------------------------
__global__ __launch_bounds__(256, 2) void z_gemm(
    ushort_t* __restrict__ VTt, const ushort_t* __restrict__ GWT)
{
    __shared__ __align__(16) ushort_t As[2][128 * 64];
    __shared__ __align__(16) ushort_t Bs[2][64 * 64];
    const int tid = threadIdx.x;
    const int lane = tid & 63;
    const int w = tid >> 6;
    const int c = lane & 15, g = lane >> 4;
    const int b = blockIdx.y;
    const int m0 = blockIdx.x * 128;
    const ushort_t* Ab = VTt + ((size_t)b * CD + m0) * SLD;
    const ushort_t* Bb = GWT + (size_t)b * 64 * CN;

    f32x4 acc[8];
#pragma unroll
    for (int i = 0; i < 8; i++) acc[i] = (f32x4){0.f, 0.f, 0.f, 0.f};

    STAGE_A128(As[0], Ab, SLD, 0);
    STAGE_B64(Bs[0], Bb, CN, 0);
    __syncthreads();
#pragma unroll 1
    for (int kt = 0; kt < 32; kt++) {
        const int cur = kt & 1;
        if (kt < 31) {
            STAGE_A128(As[cur ^ 1], Ab, SLD, kt + 1);
            STAGE_B64(Bs[cur ^ 1], Bb, CN, kt + 1);
        }
        N64_COMPUTE(As[cur], Bs[cur]);
        __syncthreads();
    }

#pragma unroll
    for (int mf = 0; mf < 2; mf++)
#pragma unroll
        for (int nf = 0; nf < 4; nf++) {
            int col = nf * 16 + c;
#pragma unroll
            for (int rr = 0; rr < 4; rr++) {
                int row = m0 + w * 32 + mf * 16 + g * 4 + rr;
                VTt[((size_t)b * CD + row) * SLD + 2048 + col] = f2bf(acc[mf * 4 + nf][rr]);
            }
        }
}

// -------------------------------------------------------------------------
// softmax_rows: row softmax over cols 0..2047 (stride SLD), fp16 in,
// bf16 out scaled by (1-a); writes tail cols 2048..2111 = a * gwp[row].
// -------------------------------------------------------------------------
__global__ __launch_bounds__(256) void softmax_rows(ushort_t* __restrict__ SP,
                                                    const ushort_t* __restrict__ GWP,
                                                    const float* __restrict__ alpha_p)
{
    const int lane = threadIdx.x & 63;
    const int row = blockIdx.x * 4 + (threadIdx.x >> 6);
    ushort_t* rp = SP + (size_t)row * SLD;

    float v[32];
    float mx = -1e30f;
#pragma unroll
    for (int ch = 0; ch < 4; ch++) {
        uint4 u = *(const uint4*)(rp + ch * 512 + lane * 8);
        const unsigned int uu[4] = {u.x, u.y, u.z, u.w};
#pragma unroll
        for (int j = 0; j < 4; j++) {
            float a = h2f((ushort_t)(uu[j] & 0xffff));
            float bq = h2f((ushort_t)(uu[j] >> 16));
            v[ch * 8 + j * 2] = a;
            v[ch * 8 + j * 2 + 1] = bq;
            mx = fmaxf(mx, fmaxf(a, bq));
        }
    }
#pragma unroll
    for (int s = 32; s > 0; s >>= 1) mx = fmaxf(mx, __shfl_xor(mx, s, 64));
    float sum = 0.f;
#pragma unroll
    for (int i = 0; i < 32; i++) {
        v[i] = __expf(v[i] - mx);
        sum += v[i];
    }
#pragma unroll
    for (int s = 32; s > 0; s >>= 1) sum += __shfl_xor(sum, s, 64);
    const float aa = sigmoidf_(alpha_p[0]);
    float sc = (1.f - aa) / sum;
#pragma unroll
    for (int ch = 0; ch < 4; ch++) {
        ushort_t t[8];
#pragma unroll
        for (int j = 0; j < 8; j++) t[j] = f2bf(v[ch * 8 + j] * sc);
        *(uint4*)(rp + ch * 512 + lane * 8) = *(uint4*)t;
    }
    if (lane < 8) {   // tail: a * gwp[row][0..63]
        const ushort_t* gp = GWP + (size_t)row * 64 + lane * 8;
        ushort_t t[8];
#pragma unroll
        for (int j = 0; j < 8; j++) t[j] = f2bf(aa * bf2f(gp[j]));
        *(uint4*)(rp + 2048 + lane * 8) = *(uint4*)t;
    }
}

// -------------------------------------------------------------------------
extern "C" void kernel_launch(void* const* d_in, const int* in_sizes, int n_in,
                              void* d_out, int out_size, void* d_ws, size_t ws_size,
                              hipStream_t stream) {
    const float* x      = (const float*)d_in[0];
    const float* W_qkv  = (const float*)d_in[1];
    const float* b_qkv  = (const float*)d_in[2];
    const float* W_proj = (const float*)d_in[3];
    const float* b_proj = (const float*)d_in[4];
    const float* W_gp   = (const float*)d_in[5];
    const float* alpha  = (const float*)d_in[6];
    float* out = (float*)d_out;

    const size_t BND    = (size_t)CB * CN * CD;        // 12,582,912 elems
    const size_t SZ_BF  = BND * 2;                     // 25,165,824 B
    const size_t SZ_VT  = (size_t)CB * CD * SLD * 2;   // 25,952,256 B
    const size_t SZ_WPT = (size_t)CD * CD * 2;         // 1,179,648 B
    const size_t SZ_GWP = (size_t)CB * CN * 64 * 2;    // 2,097,152 B
    const size_t SZ_GWT = (size_t)CB * 64 * CN * 2;    // 2,097,152 B
    const size_t SZ_WGPT= (size_t)64 * CD * 2;         // 98,304 B
    const size_t SZ_SP  = (size_t)CB * CN * SLD * 2;   // 69,206,016 B
    const size_t need = 4 * SZ_BF + SZ_VT + SZ_WPT + SZ_GWP + SZ_GWT + SZ_WGPT + SZ_SP;  // ~201 MB
    if (ws_size < need) {
        ws_fail_marker<<<1, 1, 0, stream>>>(out);
        return;
    }
    char* p = (char*)d_ws;
    ushort_t* qb   = (ushort_t*)p; p += SZ_BF;
    ushort_t* kb   = (ushort_t*)p; p += SZ_BF;
    ushort_t* vb   = (ushort_t*)p; p += SZ_BF;
    ushort_t* opb  = (ushort_t*)p; p += SZ_BF;
    ushort_t* vtb  = (ushort_t*)p; p += SZ_VT;
    ushort_t* wpt  = (ushort_t*)p; p += SZ_WPT;
    ushort_t* gwp  = (ushort_t*)p; p += SZ_GWP;
    ushort_t* gwt  = (ushort_t*)p; p += SZ_GWT;
    ushort_t* wgpt = (ushort_t*)p; p += SZ_WGPT;
    ushort_t* sp   = (ushort_t*)p; p += SZ_SP;
    // xb and wqt live inside sp (dead before s_gemm writes it)
    ushort_t* xb  = sp;
    ushort_t* wqt = sp + BND;

    cast_bf16<<<dim3((int)(BND / 8 / 256)), 256, 0, stream>>>(x, xb, (int)BND);
    wt_kernel<<<dim3(36, 12), 256, 0, stream>>>(W_qkv, wqt, CD, CDQKV);
    wt_kernel<<<dim3(12, 12), 256, 0, stream>>>(W_proj, wpt, CD, CD);
    wgpt_kernel<<<dim3(192), 256, 0, stream>>>(W_gp, wgpt);
    // qkv: M=16384, N=2304, K=768; v-blocks also emit transposed vt (fused)
    mfma_gemm<0, 12, CD, CD><<<dim3(128, 18, 1), 256, 0, stream>>>(
        xb, wqt, b_qkv, qb, kb, vb, vtb, nullptr, nullptr);
    gw_gemm<<<dim3(128), 256, 0, stream>>>(vb, wgpt, gwp, gwt);
    z_gemm<<<dim3(6, 8), 256, 0, stream>>>(vtb, gwt);
    // s: per-batch 2048x2048, K=768, fp16 out * scale * G (T1 batch swizzle)
    s_gemm<<<dim3(2048), 256, 0, stream>>>(qb, kb, gwp, sp);
    softmax_rows<<<dim3(4096), 256, 0, stream>>>(sp, gwp, alpha);
    // pv: O = P' @ B'^T with K = 2112 (P|a*gw concat), T1 swizzle, n-fastest
    mfma_gemm<2, 33, SLD, SLD><<<dim3(768), 256, 0, stream>>>(
        sp, vtb, nullptr, nullptr, nullptr, nullptr, nullptr, opb, nullptr);
    // proj: fp32 out + bias
    mfma_gemm<1, 12, CD, CD><<<dim3(128, 6, 1), 256, 0, stream>>>(
        opb, wpt, b_proj, nullptr, nullptr, nullptr, nullptr, nullptr, out);
}

// Round 13
// 357.335 us; speedup vs baseline: 1.0128x; 1.0128x over previous
//
#include <hip/hip_runtime.h>
#include <hip/hip_bf16.h>
#include <math.h>

// Problem constants
#define CB 8        // batch
#define CN 2048     // seq len
#define CD 768      // dim
#define CDQKV 2304  // 3*dim
#define NG 49       // groups
#define SLD 2112    // padded K-row stride for P|a*gw concat (2048 + 64)

typedef unsigned short ushort_t;
typedef __attribute__((ext_vector_type(8))) short bf16x8;
typedef __attribute__((ext_vector_type(4))) float f32x4;

__device__ __forceinline__ float bf2f(ushort_t u) {
    unsigned int x = ((unsigned int)u) << 16;
    return __builtin_bit_cast(float, x);
}
__device__ __forceinline__ ushort_t f2bf(float f) {
    unsigned int u = __builtin_bit_cast(unsigned int, f);
    u += 0x7fff + ((u >> 16) & 1);   // RNE
    return (ushort_t)(u >> 16);
}
__device__ __forceinline__ ushort_t f2h(float f) {
    _Float16 h = (_Float16)f;
    return __builtin_bit_cast(ushort_t, h);
}
__device__ __forceinline__ float h2f(ushort_t u) {
    return (float)__builtin_bit_cast(_Float16, u);
}
__device__ __forceinline__ float sigmoidf_(float x) { return 1.f / (1.f + __expf(-x)); }

__device__ __forceinline__ void gload_lds16(const ushort_t* g, ushort_t* l) {
    __builtin_amdgcn_global_load_lds((const __attribute__((address_space(1))) void*)g,
                                     (__attribute__((address_space(3))) void*)l, 16, 0, 0);
}

// -------------------------------------------------------------------------
__global__ void ws_fail_marker(float* out) {
    if (threadIdx.x == 0 && blockIdx.x == 0) out[0] = 31337.0f;
}

// -------------------------------------------------------------------------
__global__ __launch_bounds__(256) void cast_bf16(const float* __restrict__ X,
                                                 ushort_t* __restrict__ XB, int n)
{
    int i = (blockIdx.x * 256 + threadIdx.x) * 8;
    if (i >= n) return;
    float4 a = *(const float4*)(X + i);
    float4 b = *(const float4*)(X + i + 4);
    ushort_t t[8];
    t[0] = f2bf(a.x); t[1] = f2bf(a.y); t[2] = f2bf(a.z); t[3] = f2bf(a.w);
    t[4] = f2bf(b.x); t[5] = f2bf(b.y); t[6] = f2bf(b.z); t[7] = f2bf(b.w);
    *(uint4*)(XB + i) = *(uint4*)t;
}

// -------------------------------------------------------------------------
__global__ __launch_bounds__(256) void wt_kernel(const float* __restrict__ W,
                                                 ushort_t* __restrict__ WT,
                                                 int rows, int cols)
{
    __shared__ ushort_t tile[64][72];
    const int bx = blockIdx.x, by = blockIdx.y;
    const int t = threadIdx.x;
    const int r = t >> 2, cp = (t & 3) * 16;
    const float* src = W + (size_t)(by * 64 + r) * cols + bx * 64 + cp;
    ushort_t tmp[16];
#pragma unroll
    for (int i = 0; i < 16; i += 4) {
        float4 v = *(const float4*)(src + i);
        tmp[i + 0] = f2bf(v.x); tmp[i + 1] = f2bf(v.y);
        tmp[i + 2] = f2bf(v.z); tmp[i + 3] = f2bf(v.w);
    }
    *(uint4*)&tile[r][cp] = *(uint4*)tmp;
    *(uint4*)&tile[r][cp + 8] = *(uint4*)(tmp + 8);
    __syncthreads();
#pragma unroll
    for (int i = 0; i < 16; i++) tmp[i] = tile[cp + i][r];
    ushort_t* dst = WT + (size_t)(bx * 64 + r) * rows + by * 64 + cp;
    *(uint4*)dst = *(uint4*)tmp;
    *(uint4*)(dst + 8) = *(uint4*)(tmp + 8);
}

// -------------------------------------------------------------------------
__global__ __launch_bounds__(256) void wgpt_kernel(const float* __restrict__ Wg,
                                                   ushort_t* __restrict__ WGPT)
{
    int idx = blockIdx.x * 256 + threadIdx.x;   // 64*768 = 49152
    if (idx >= 64 * CD) return;
    int gg = idx / CD, k = idx % CD;
    WGPT[idx] = (gg < NG) ? f2bf(Wg[(size_t)k * NG + gg]) : (ushort_t)0;
}

// =========================================================================
// 128x128 2-phase machinery (proven best measured structure this session):
// BK=64, 256 thr = 4 waves (2x2 of 64x64), double-buffered LDS via
// global_load_lds w=16, source-preswizzled XOR (rule #21), 2-barrier loop.
// =========================================================================
#define GEN_STAGE(dstA_, dstB_, kt_, Abase_, Bbase_, lda_, ldb_) do {          \
    _Pragma("unroll")                                                          \
    for (int _p = 0; _p < 4; _p++) {                                           \
        int _idx = _p * 256 + tid;                                             \
        int _row = _idx >> 3;                                                  \
        int _lsl = (_idx & 7) ^ (_row & 7);                                    \
        gload_lds16((Abase_) + (size_t)_row * (lda_) + (size_t)(kt_) * 64 + _lsl * 8, \
                    (dstA_) + _idx * 8);                                       \
        gload_lds16((Bbase_) + (size_t)_row * (ldb_) + (size_t)(kt_) * 64 + _lsl * 8, \
                    (dstB_) + _idx * 8);                                       \
    } } while (0)

#define G_COMPUTE(srcA_, srcB_) do {                                           \
    _Pragma("unroll")                                                          \
    for (int _ks = 0; _ks < 2; _ks++) {                                        \
        bf16x8 _af[4], _bf[4];                                                 \
        _Pragma("unroll")                                                      \
        for (int _f = 0; _f < 4; _f++) {                                       \
            int _ra = wr * 64 + _f * 16 + c;                                   \
            int _pa = (_ks * 4 + g) ^ (_ra & 7);                               \
            _af[_f] = *(const bf16x8*)((srcA_) + _ra * 64 + _pa * 8);          \
            int _rb = wc * 64 + _f * 16 + c;                                   \
            int _pb = (_ks * 4 + g) ^ (_rb & 7);                               \
            _bf[_f] = *(const bf16x8*)((srcB_) + _rb * 64 + _pb * 8);          \
        }                                                                      \
        _Pragma("unroll")                                                      \
        for (int _mf = 0; _mf < 4; _mf++)                                      \
            _Pragma("unroll")                                                  \
            for (int _nf = 0; _nf < 4; _nf++)                                  \
                acc[_mf * 4 + _nf] = __builtin_amdgcn_mfma_f32_16x16x32_bf16(  \
                    _af[_mf], _bf[_nf], acc[_mf * 4 + _nf], 0, 0, 0);          \
    } } while (0)

#define STAGE_A128(dst_, base_, ld_, kt_) do {                                 \
    _Pragma("unroll")                                                          \
    for (int _p = 0; _p < 4; _p++) {                                           \
        int _idx = _p * 256 + tid;                                             \
        int _row = _idx >> 3;                                                  \
        int _lsl = (_idx & 7) ^ (_row & 7);                                    \
        gload_lds16((base_) + (size_t)_row * (ld_) + (size_t)(kt_) * 64 + _lsl * 8, \
                    (dst_) + _idx * 8);                                        \
    } } while (0)

#define STAGE_B64(dst_, base_, ld_, kt_) do {                                  \
    _Pragma("unroll")                                                          \
    for (int _p = 0; _p < 2; _p++) {                                           \
        int _idx = _p * 256 + tid;                                             \
        int _row = _idx >> 3;                                                  \
        int _lsl = (_idx & 7) ^ (_row & 7);                                    \
        gload_lds16((base_) + (size_t)_row * (ld_) + (size_t)(kt_) * 64 + _lsl * 8, \
                    (dst_) + _idx * 8);                                        \
    } } while (0)

#define N64_COMPUTE(srcA_, srcB_) do {                                         \
    _Pragma("unroll")                                                          \
    for (int _ks = 0; _ks < 2; _ks++) {                                        \
        bf16x8 _af[2], _bf[4];                                                 \
        _Pragma("unroll")                                                      \
        for (int _f = 0; _f < 2; _f++) {                                       \
            int _ra = w * 32 + _f * 16 + c;                                    \
            int _pa = (_ks * 4 + g) ^ (_ra & 7);                               \
            _af[_f] = *(const bf16x8*)((srcA_) + _ra * 64 + _pa * 8);          \
        }                                                                      \
        _Pragma("unroll")                                                      \
        for (int _f = 0; _f < 4; _f++) {                                       \
            int _rb = _f * 16 + c;                                             \
            int _pb = (_ks * 4 + g) ^ (_rb & 7);                               \
            _bf[_f] = *(const bf16x8*)((srcB_) + _rb * 64 + _pb * 8);          \
        }                                                                      \
        _Pragma("unroll")                                                      \
        for (int _mf = 0; _mf < 2; _mf++)                                      \
            _Pragma("unroll")                                                  \
            for (int _nf = 0; _nf < 4; _nf++)                                  \
                acc[_mf * 4 + _nf] = __builtin_amdgcn_mfma_f32_16x16x32_bf16(  \
                    _af[_mf], _bf[_nf], acc[_mf * 4 + _nf], 0, 0, 0);          \
    } } while (0)

// -------------------------------------------------------------------------
// mfma_gemm: 128x128 C = A @ B^T (+bias), 2-phase.
// OUTMODE 0: split bf16 q/k/v + bias (grid (128,18,1)).
//         1: fp32 out + bias        (grid (128,6,1)).
//         2: bf16 out, per-batch A/B panels, K=2112 pv.
//            1-D grid (768) with batch-chunked XCD swizzle (T1): each XCD
//            owns one batch -> P/vt panels stay resident in its L2.
// -------------------------------------------------------------------------
template <int OUTMODE, int NK, int LDA, int LDB>
__global__ __launch_bounds__(256, 2) void mfma_gemm(
    const ushort_t* __restrict__ Ag, const ushort_t* __restrict__ Bg,
    const float* __restrict__ bias,
    ushort_t* __restrict__ Qd, ushort_t* __restrict__ Kd, ushort_t* __restrict__ Vd,
    ushort_t* __restrict__ OB, float* __restrict__ OF)
{
    __shared__ __align__(16) ushort_t As[2][128 * 64];
    __shared__ __align__(16) ushort_t Bs[2][128 * 64];
    const int tid = threadIdx.x;
    const int lane = tid & 63;
    const int w = tid >> 6;
    const int c = lane & 15, g = lane >> 4;
    const int wr = w >> 1, wc = w & 1;

    int m0, n0, b;
    const ushort_t* Ab;
    const ushort_t* Bb;
    if (OUTMODE == 2) {
        // T1 batch-chunk swizzle: flat grid 768 = 96/XCD; idx/96 = batch.
        const int flat = blockIdx.x;
        const int idx = (flat & 7) * 96 + (flat >> 3);
        b = idx / 96;
        const int rem = idx % 96;
        m0 = (rem & 15) * 128;
        n0 = (rem >> 4) * 128;
        Ab = Ag + ((size_t)b * CN + m0) * LDA;     // P rows, stride SLD
        Bb = Bg + ((size_t)b * CD + n0) * LDB;     // V^T rows (d), stride SLD
    } else {
        m0 = blockIdx.x * 128;
        n0 = blockIdx.y * 128;
        b = 0;
        Ab = Ag + (size_t)m0 * LDA;
        Bb = Bg + (size_t)n0 * LDB;
    }

    f32x4 acc[16];
#pragma unroll
    for (int i = 0; i < 16; i++) acc[i] = (f32x4){0.f, 0.f, 0.f, 0.f};

    GEN_STAGE(As[0], Bs[0], 0, Ab, Bb, LDA, LDB);
    __syncthreads();
#pragma unroll 1
    for (int kt = 0; kt < NK; kt++) {
        const int cur = kt & 1;
        if (kt < NK - 1) GEN_STAGE(As[cur ^ 1], Bs[cur ^ 1], kt + 1, Ab, Bb, LDA, LDB);
        G_COMPUTE(As[cur], Bs[cur]);
        __syncthreads();
    }

    if (OUTMODE == 0) {
        const int seg = n0 / CD;
        const int nl0 = n0 % CD;
        ushort_t* dst = (seg == 0) ? Qd : (seg == 1) ? Kd : Vd;
#pragma unroll
        for (int nf = 0; nf < 4; nf++) {
            float bv = bias[n0 + wc * 64 + nf * 16 + c];
            int n = nl0 + wc * 64 + nf * 16 + c;
#pragma unroll
            for (int mf = 0; mf < 4; mf++) {
#pragma unroll
                for (int r = 0; r < 4; r++) {
                    int m = m0 + wr * 64 + mf * 16 + g * 4 + r;
                    dst[(size_t)m * CD + n] = f2bf(acc[mf * 4 + nf][r] + bv);
                }
            }
        }
    } else if (OUTMODE == 1) {
#pragma unroll
        for (int nf = 0; nf < 4; nf++) {
            int n = n0 + wc * 64 + nf * 16 + c;
            float bv = bias[n];
#pragma unroll
            for (int mf = 0; mf < 4; mf++) {
#pragma unroll
                for (int r = 0; r < 4; r++) {
                    int m = m0 + wr * 64 + mf * 16 + g * 4 + r;
                    OF[(size_t)m * CD + n] = acc[mf * 4 + nf][r] + bv;
                }
            }
        }
    } else {
        ushort_t* OPb = OB + ((size_t)b * CN + m0) * CD;
#pragma unroll
        for (int nf = 0; nf < 4; nf++) {
            int n = n0 + wc * 64 + nf * 16 + c;
#pragma unroll
            for (int mf = 0; mf < 4; mf++) {
#pragma unroll
                for (int r = 0; r < 4; r++) {
                    int m = wr * 64 + mf * 16 + g * 4 + r;
                    OPb[(size_t)m * CD + n] = f2bf(acc[mf * 4 + nf][r]);
                }
            }
        }
    }
}

// -------------------------------------------------------------------------
// s_gemm: S = (q.k)*scale*G, fp16 out at row-stride SLD. 128^2, 2-phase,
// G-affinity via 32 upfront MFMAs with frags straight from global (L2-hot).
// 1-D grid (2048) with batch-chunked XCD swizzle (T1): each XCD owns one
// batch -> its q/k panels (6.3 MB) stay L2-resident instead of B-panels
// being refetched by all 8 XCDs.
// -------------------------------------------------------------------------
__global__ __launch_bounds__(256, 2) void s_gemm(
    const ushort_t* __restrict__ Qb, const ushort_t* __restrict__ Kb,
    const ushort_t* __restrict__ GWP, ushort_t* __restrict__ S)
{
    __shared__ __align__(16) ushort_t As[2][128 * 64];
    __shared__ __align__(16) ushort_t Bs[2][128 * 64];
    const int tid = threadIdx.x;
    const int lane = tid & 63;
    const int w = tid >> 6;
    const int c = lane & 15, g = lane >> 4;
    const int wr = w >> 1, wc = w & 1;

    // T1 batch-chunk swizzle: flat grid 2048 = 256/XCD; idx>>8 = batch.
    const int flat = blockIdx.x;
    const int idx = (flat & 7) * 256 + (flat >> 3);
    const int b = idx >> 8;
    const int m0 = ((idx >> 4) & 15) * 128;
    const int n0 = (idx & 15) * 128;

    const ushort_t* Ab = Qb + ((size_t)b * CN + m0) * CD;
    const ushort_t* Bb = Kb + ((size_t)b * CN + n0) * CD;

    f32x4 acc[16], gacc[16];
#pragma unroll
    for (int i = 0; i < 16; i++) {
        acc[i] = (f32x4){0.f, 0.f, 0.f, 0.f};
        gacc[i] = (f32x4){0.f, 0.f, 0.f, 0.f};
    }

    GEN_STAGE(As[0], Bs[0], 0, Ab, Bb, CD, CD);

    {
        const ushort_t* Gq = GWP + ((size_t)b * CN + m0) * 64;
        const ushort_t* Gk = GWP + ((size_t)b * CN + n0) * 64;
        bf16x8 gqf[2][4], gkf[2][4];
#pragma unroll
        for (int ks = 0; ks < 2; ks++)
#pragma unroll
            for (int f = 0; f < 4; f++) {
                gqf[ks][f] = *(const bf16x8*)(Gq + (size_t)(wr * 64 + f * 16 + c) * 64 + ks * 32 + g * 8);
                gkf[ks][f] = *(const bf16x8*)(Gk + (size_t)(wc * 64 + f * 16 + c) * 64 + ks * 32 + g * 8);
            }
#pragma unroll
        for (int ks = 0; ks < 2; ks++)
#pragma unroll
            for (int mf = 0; mf < 4; mf++)
#pragma unroll
                for (int nf = 0; nf < 4; nf++)
                    gacc[mf * 4 + nf] = __builtin_amdgcn_mfma_f32_16x16x32_bf16(
                        gqf[ks][mf], gkf[ks][nf], gacc[mf * 4 + nf], 0, 0, 0);
    }

    __syncthreads();
#pragma unroll 1
    for (int kt = 0; kt < 12; kt++) {
        const int cur = kt & 1;
        if (kt < 11) GEN_STAGE(As[cur ^ 1], Bs[cur ^ 1], kt + 1, Ab, Bb, CD, CD);
        G_COMPUTE(As[cur], Bs[cur]);
        __syncthreads();
    }

    ushort_t* Sb = S + ((size_t)b * CN + m0) * SLD + n0;
    const float scale = 0.03608439182435161f;  // 768^-0.5
#pragma unroll
    for (int nf = 0; nf < 4; nf++) {
        int n = wc * 64 + nf * 16 + c;
#pragma unroll
        for (int mf = 0; mf < 4; mf++) {
#pragma unroll
            for (int r = 0; r < 4; r++) {
                int m = wr * 64 + mf * 16 + g * 4 + r;
                float z = acc[mf * 4 + nf][r] * scale * gacc[mf * 4 + nf][r];
                Sb[(size_t)m * SLD + n] = f2h(z);
            }
        }
    }
}

// -------------------------------------------------------------------------
// gw_gemm: gw = softmax49(gelu_exact(v @ W_gp)) via MFMA, fused epilogue.
// -------------------------------------------------------------------------
__global__ __launch_bounds__(256, 2) void gw_gemm(
    const ushort_t* __restrict__ Vb, const ushort_t* __restrict__ WGPT,
    ushort_t* __restrict__ GWP, ushort_t* __restrict__ GWT)
{
    __shared__ __align__(16) ushort_t As[2][128 * 64];
    __shared__ __align__(16) ushort_t Bs[2][64 * 64];
    const int tid = threadIdx.x;
    const int lane = tid & 63;
    const int w = tid >> 6;
    const int c = lane & 15, g = lane >> 4;
    const int row0 = blockIdx.x * 128;
    const ushort_t* Ab = Vb + (size_t)row0 * CD;

    f32x4 acc[8];
#pragma unroll
    for (int i = 0; i < 8; i++) acc[i] = (f32x4){0.f, 0.f, 0.f, 0.f};

    STAGE_A128(As[0], Ab, CD, 0);
    STAGE_B64(Bs[0], WGPT, CD, 0);
    __syncthreads();
#pragma unroll 1
    for (int kt = 0; kt < 12; kt++) {
        const int cur = kt & 1;
        if (kt < 11) {
            STAGE_A128(As[cur ^ 1], Ab, CD, kt + 1);
            STAGE_B64(Bs[cur ^ 1], WGPT, CD, kt + 1);
        }
        N64_COMPUTE(As[cur], Bs[cur]);
        __syncthreads();
    }

    float gl[2][4][4];
#pragma unroll
    for (int mf = 0; mf < 2; mf++)
#pragma unroll
        for (int nf = 0; nf < 4; nf++) {
            int col = nf * 16 + c;
#pragma unroll
            for (int rr = 0; rr < 4; rr++) {
                float xx = acc[mf * 4 + nf][rr];
                float ge = 0.5f * xx * (1.f + erff(xx * 0.7071067811865475f));
                gl[mf][nf][rr] = (col < NG) ? ge : -1e30f;
            }
        }
#pragma unroll
    for (int mf = 0; mf < 2; mf++) {
#pragma unroll
        for (int rr = 0; rr < 4; rr++) {
            float m = fmaxf(fmaxf(gl[mf][0][rr], gl[mf][1][rr]),
                            fmaxf(gl[mf][2][rr], gl[mf][3][rr]));
#pragma unroll
            for (int s = 1; s < 16; s <<= 1) m = fmaxf(m, __shfl_xor(m, s, 64));
            float ssum = 0.f;
#pragma unroll
            for (int nf = 0; nf < 4; nf++) {
                int col = nf * 16 + c;
                float e = (col < NG) ? __expf(gl[mf][nf][rr] - m) : 0.f;
                gl[mf][nf][rr] = e;
                ssum += e;
            }
#pragma unroll
            for (int s = 1; s < 16; s <<= 1) ssum += __shfl_xor(ssum, s, 64);
            float inv = 1.f / ssum;
            int row = row0 + w * 32 + mf * 16 + g * 4 + rr;
            int bb = row >> 11, nn = row & 2047;
#pragma unroll
            for (int nf = 0; nf < 4; nf++) {
                int col = nf * 16 + c;
                ushort_t wv = f2bf(gl[mf][nf][rr] * inv);
                GWP[(size_t)row * 64 + col] = wv;
                GWT[((size_t)bb * 64 + col) * CN + nn] = wv;
            }
        }
    }
}

// -------------------------------------------------------------------------
// z_gemm: Z^T[b][d][g] = sum_n vt[b][d][n]*gwt[b][g][n]; writes the TAIL
// columns (2048..2111) of the stride-2112 vt buffer.
// -------------------------------------------------------------------------
__global__ __launch_bounds__(256, 2) void z_gemm(
    ushort_t* __restrict__ VTt, const ushort_t* __restrict__ GWT)
{
    __shared__ __align__(16) ushort_t As[2][128 * 64];
    __shared__ __align__(16) ushort_t Bs[2][64 * 64];
    const int tid = threadIdx.x;
    const int lane = tid & 63;
    const int w = tid >> 6;
    const int c = lane & 15, g = lane >> 4;
    const int b = blockIdx.y;
    const int m0 = blockIdx.x * 128;
    const ushort_t* Ab = VTt + ((size_t)b * CD + m0) * SLD;
    const ushort_t* Bb = GWT + (size_t)b * 64 * CN;

    f32x4 acc[8];
#pragma unroll
    for (int i = 0; i < 8; i++) acc[i] = (f32x4){0.f, 0.f, 0.f, 0.f};

    STAGE_A128(As[0], Ab, SLD, 0);
    STAGE_B64(Bs[0], Bb, CN, 0);
    __syncthreads();
#pragma unroll 1
    for (int kt = 0; kt < 32; kt++) {
        const int cur = kt & 1;
        if (kt < 31) {
            STAGE_A128(As[cur ^ 1], Ab, SLD, kt + 1);
            STAGE_B64(Bs[cur ^ 1], Bb, CN, kt + 1);
        }
        N64_COMPUTE(As[cur], Bs[cur]);
        __syncthreads();
    }

#pragma unroll
    for (int mf = 0; mf < 2; mf++)
#pragma unroll
        for (int nf = 0; nf < 4; nf++) {
            int col = nf * 16 + c;
#pragma unroll
            for (int rr = 0; rr < 4; rr++) {
                int row = m0 + w * 32 + mf * 16 + g * 4 + rr;
                VTt[((size_t)b * CD + row) * SLD + 2048 + col] = f2bf(acc[mf * 4 + nf][rr]);
            }
        }
}

// -------------------------------------------------------------------------
// softmax_rows: row softmax over cols 0..2047 (stride SLD), fp16 in,
// bf16 out scaled by (1-a); writes tail cols 2048..2111 = a * gwp[row].
// -------------------------------------------------------------------------
__global__ __launch_bounds__(256) void softmax_rows(ushort_t* __restrict__ SP,
                                                    const ushort_t* __restrict__ GWP,
                                                    const float* __restrict__ alpha_p)
{
    const int lane = threadIdx.x & 63;
    const int row = blockIdx.x * 4 + (threadIdx.x >> 6);
    ushort_t* rp = SP + (size_t)row * SLD;

    float v[32];
    float mx = -1e30f;
#pragma unroll
    for (int ch = 0; ch < 4; ch++) {
        uint4 u = *(const uint4*)(rp + ch * 512 + lane * 8);
        const unsigned int uu[4] = {u.x, u.y, u.z, u.w};
#pragma unroll
        for (int j = 0; j < 4; j++) {
            float a = h2f((ushort_t)(uu[j] & 0xffff));
            float bq = h2f((ushort_t)(uu[j] >> 16));
            v[ch * 8 + j * 2] = a;
            v[ch * 8 + j * 2 + 1] = bq;
            mx = fmaxf(mx, fmaxf(a, bq));
        }
    }
#pragma unroll
    for (int s = 32; s > 0; s >>= 1) mx = fmaxf(mx, __shfl_xor(mx, s, 64));
    float sum = 0.f;
#pragma unroll
    for (int i = 0; i < 32; i++) {
        v[i] = __expf(v[i] - mx);
        sum += v[i];
    }
#pragma unroll
    for (int s = 32; s > 0; s >>= 1) sum += __shfl_xor(sum, s, 64);
    const float aa = sigmoidf_(alpha_p[0]);
    float sc = (1.f - aa) / sum;
#pragma unroll
    for (int ch = 0; ch < 4; ch++) {
        ushort_t t[8];
#pragma unroll
        for (int j = 0; j < 8; j++) t[j] = f2bf(v[ch * 8 + j] * sc);
        *(uint4*)(rp + ch * 512 + lane * 8) = *(uint4*)t;
    }
    if (lane < 8) {   // tail: a * gwp[row][0..63]
        const ushort_t* gp = GWP + (size_t)row * 64 + lane * 8;
        ushort_t t[8];
#pragma unroll
        for (int j = 0; j < 8; j++) t[j] = f2bf(aa * bf2f(gp[j]));
        *(uint4*)(rp + 2048 + lane * 8) = *(uint4*)t;
    }
}

// -------------------------------------------------------------------------
// vt_transpose: vt[b][d][n] = v[b][n][d] into stride-SLD buffer
// -------------------------------------------------------------------------
__global__ __launch_bounds__(256) void vt_transpose(const ushort_t* __restrict__ VB,
                                                    ushort_t* __restrict__ VTt)
{
    __shared__ ushort_t tile[64][72];
    const int bx = blockIdx.x, by = blockIdx.y, b = blockIdx.z;
    const int t = threadIdx.x;
    const int r = t >> 2, cp = (t & 3) * 16;
    const ushort_t* src = VB + ((size_t)b * CN + bx * 64 + r) * CD + by * 64 + cp;
    *(uint4*)&tile[r][cp] = *(const uint4*)src;
    *(uint4*)&tile[r][cp + 8] = *(const uint4*)(src + 8);
    __syncthreads();
    ushort_t tmp[16];
#pragma unroll
    for (int i = 0; i < 16; i++) tmp[i] = tile[cp + i][r];
    ushort_t* dst = VTt + ((size_t)b * CD + by * 64 + r) * SLD + bx * 64 + cp;
    *(uint4*)dst = *(uint4*)tmp;
    *(uint4*)(dst + 8) = *(uint4*)(tmp + 8);
}

// -------------------------------------------------------------------------
extern "C" void kernel_launch(void* const* d_in, const int* in_sizes, int n_in,
                              void* d_out, int out_size, void* d_ws, size_t ws_size,
                              hipStream_t stream) {
    const float* x      = (const float*)d_in[0];
    const float* W_qkv  = (const float*)d_in[1];
    const float* b_qkv  = (const float*)d_in[2];
    const float* W_proj = (const float*)d_in[3];
    const float* b_proj = (const float*)d_in[4];
    const float* W_gp   = (const float*)d_in[5];
    const float* alpha  = (const float*)d_in[6];
    float* out = (float*)d_out;

    const size_t BND    = (size_t)CB * CN * CD;        // 12,582,912 elems
    const size_t SZ_BF  = BND * 2;                     // 25,165,824 B
    const size_t SZ_VT  = (size_t)CB * CD * SLD * 2;   // 25,952,256 B
    const size_t SZ_WPT = (size_t)CD * CD * 2;         // 1,179,648 B
    const size_t SZ_GWP = (size_t)CB * CN * 64 * 2;    // 2,097,152 B
    const size_t SZ_GWT = (size_t)CB * 64 * CN * 2;    // 2,097,152 B
    const size_t SZ_WGPT= (size_t)64 * CD * 2;         // 98,304 B
    const size_t SZ_SP  = (size_t)CB * CN * SLD * 2;   // 69,206,016 B
    const size_t need = 4 * SZ_BF + SZ_VT + SZ_WPT + SZ_GWP + SZ_GWT + SZ_WGPT + SZ_SP;  // ~201 MB
    if (ws_size < need) {
        ws_fail_marker<<<1, 1, 0, stream>>>(out);
        return;
    }
    char* p = (char*)d_ws;
    ushort_t* qb   = (ushort_t*)p; p += SZ_BF;
    ushort_t* kb   = (ushort_t*)p; p += SZ_BF;
    ushort_t* vb   = (ushort_t*)p; p += SZ_BF;
    ushort_t* opb  = (ushort_t*)p; p += SZ_BF;
    ushort_t* vtb  = (ushort_t*)p; p += SZ_VT;
    ushort_t* wpt  = (ushort_t*)p; p += SZ_WPT;
    ushort_t* gwp  = (ushort_t*)p; p += SZ_GWP;
    ushort_t* gwt  = (ushort_t*)p; p += SZ_GWT;
    ushort_t* wgpt = (ushort_t*)p; p += SZ_WGPT;
    ushort_t* sp   = (ushort_t*)p; p += SZ_SP;
    // xb and wqt live inside sp (dead before s_gemm writes it)
    ushort_t* xb  = sp;
    ushort_t* wqt = sp + BND;

    cast_bf16<<<dim3((int)(BND / 8 / 256)), 256, 0, stream>>>(x, xb, (int)BND);
    wt_kernel<<<dim3(36, 12), 256, 0, stream>>>(W_qkv, wqt, CD, CDQKV);
    wt_kernel<<<dim3(12, 12), 256, 0, stream>>>(W_proj, wpt, CD, CD);
    wgpt_kernel<<<dim3(192), 256, 0, stream>>>(W_gp, wgpt);
    // qkv: M=16384, N=2304, K=768  (128^2 2-phase, default mapping)
    mfma_gemm<0, 12, CD, CD><<<dim3(128, 18, 1), 256, 0, stream>>>(
        xb, wqt, b_qkv, qb, kb, vb, nullptr, nullptr);
    gw_gemm<<<dim3(128), 256, 0, stream>>>(vb, wgpt, gwp, gwt);
    vt_transpose<<<dim3(32, 12, 8), 256, 0, stream>>>(vb, vtb);
    z_gemm<<<dim3(6, 8), 256, 0, stream>>>(vtb, gwt);
    // s: per-batch 2048x2048, K=768, fp16 out * scale * G (T1 batch swizzle)
    s_gemm<<<dim3(2048), 256, 0, stream>>>(qb, kb, gwp, sp);
    softmax_rows<<<dim3(4096), 256, 0, stream>>>(sp, gwp, alpha);
    // pv: O = P' @ B'^T with K = 2112 (P|a*gw concat), T1 batch swizzle
    mfma_gemm<2, 33, SLD, SLD><<<dim3(768), 256, 0, stream>>>(
        sp, vtb, nullptr, nullptr, nullptr, nullptr, opb, nullptr);
    // proj: fp32 out + bias
    mfma_gemm<1, 12, CD, CD><<<dim3(128, 6, 1), 256, 0, stream>>>(
        opb, wpt, b_proj, nullptr, nullptr, nullptr, nullptr, out);
}